// Round 3
// baseline (9336.781 us; speedup 1.0000x reference)
//
#include <hip/hip_runtime.h>
#include <math.h>

#define B_N 64
#define T_N 3072
#define FIN 128
#define TP 1024      // conv output length
#define COUT 64
#define HID 256
#define G4 1024      // 4*HID
#define OUT_N 10
#define NCHUNK 24
#define CHUNK_T (T_N / NCHUNK)   // 128

typedef _Float16 h2_t __attribute__((ext_vector_type(2)));

#if defined(__has_builtin)
#if __has_builtin(__builtin_amdgcn_fdot2)
#define HAVE_FDOT2 1
#endif
#endif

__device__ __forceinline__ float fdot2(unsigned w, unsigned h, float acc) {
#ifdef HAVE_FDOT2
    return __builtin_amdgcn_fdot2(__builtin_bit_cast(h2_t, w),
                                  __builtin_bit_cast(h2_t, h), acc, false);
#else
    h2_t wv = __builtin_bit_cast(h2_t, w), hv = __builtin_bit_cast(h2_t, h);
    return acc + (float)wv.x * (float)hv.x + (float)wv.y * (float)hv.y;
#endif
}

__device__ __forceinline__ unsigned pack2(float a, float b) {
    unsigned la = (unsigned)__builtin_bit_cast(unsigned short, (_Float16)a);
    unsigned lb = (unsigned)__builtin_bit_cast(unsigned short, (_Float16)b);
    return la | (lb << 16);
}

// ---------------------------------------------------------------------------
// Pack LSTM weights to f16x2, layout [dword d][gate col j] so the LSTM's
// register-init loads are lane-coalesced.
//  whhR: [128][1024], wihR: [32][1024]
// grid 1024 (j), 128 threads (d).
// ---------------------------------------------------------------------------
__global__ void pack_weights(const float* __restrict__ w_ih,
                             const float* __restrict__ w_hh,
                             unsigned* __restrict__ whhR,
                             unsigned* __restrict__ wihR) {
    int j = blockIdx.x, d = threadIdx.x;   // d in [0,128)
    const float* wr = w_hh + j * HID;
    whhR[d * 1024 + j] = pack2(wr[2 * d], wr[2 * d + 1]);
    if (d < 32) {
        wihR[d * 1024 + j] = pack2(w_ih[j * COUT + 2 * d], w_ih[j * COUT + 2 * d + 1]);
    }
}

// conv weight permute: wc2[j][oc], j = kk*128+ic
__global__ void prep_conv_w(const float* __restrict__ conv_w, float* __restrict__ wc2) {
    int i = blockIdx.x * 256 + threadIdx.x;
    if (i < 24576) {
        int j = i >> 6, oc = i & 63;
        int kk = j >> 7, ic = j & 127;
        wc2[i] = conv_w[(oc * 128 + ic) * 3 + kk];
    }
}

// ---------------------------------------------------------------------------
// partial sum-of-squares over time (F.normalize along dim=1)
// ---------------------------------------------------------------------------
__global__ void norm_partial(const float* __restrict__ in, float* __restrict__ part) {
    int b = blockIdx.x, ch = blockIdx.y, f = threadIdx.x;
    const float* p = in + ((size_t)b * T_N + (size_t)ch * CHUNK_T) * FIN + f;
    float s0 = 0.f, s1 = 0.f, s2 = 0.f, s3 = 0.f;
#pragma unroll
    for (int r = 0; r < CHUNK_T; r += 4) {
        float v0 = p[(r + 0) * FIN];
        float v1 = p[(r + 1) * FIN];
        float v2 = p[(r + 2) * FIN];
        float v3 = p[(r + 3) * FIN];
        s0 += v0 * v0; s1 += v1 * v1; s2 += v2 * v2; s3 += v3 * v3;
    }
    part[(b * NCHUNK + ch) * FIN + f] = (s0 + s1) + (s2 + s3);
}

// ---------------------------------------------------------------------------
// normalize + conv1d(k=3,stride=3) + bias + relu  (stride==K -> GEMM)
// ---------------------------------------------------------------------------
__global__ __launch_bounds__(256) void conv_relu(
        const float* __restrict__ in, const float* __restrict__ part,
        const float* __restrict__ wc2, const float* __restrict__ cb,
        float* __restrict__ X) {
    __shared__ __align__(16) float xs[16 * 384];
    __shared__ __align__(16) float wsh[96 * 64];
    __shared__ float invn[FIN];

    int b = blockIdx.x, tile = blockIdx.y;
    int tid = threadIdx.x;

    if (tid < FIN) {
        float s = 0.f;
#pragma unroll
        for (int c = 0; c < NCHUNK; c++) s += part[(b * NCHUNK + c) * FIN + tid];
        invn[tid] = rsqrtf(fmaxf(s, 1e-24f));
    }
    __syncthreads();

    const float* ip = in + ((size_t)b * T_N + (size_t)tile * 48) * FIN;
    for (int i = tid; i < 6144; i += 256) xs[i] = ip[i] * invn[i & 127];

    int oc = tid & 63, tq = tid >> 6;
    float acc0 = 0.f, acc1 = 0.f, acc2 = 0.f, acc3 = 0.f;
    const float* xb = xs + tq * 4 * 384;

    for (int c = 0; c < 4; c++) {
        __syncthreads();
        for (int i = tid; i < 6144; i += 256) wsh[i] = wc2[c * 6144 + i];
        __syncthreads();
#pragma unroll 8
        for (int jj = 0; jj < 96; jj += 4) {
            int j = c * 96 + jj;
            float w0 = wsh[(jj + 0) * 64 + oc];
            float w1 = wsh[(jj + 1) * 64 + oc];
            float w2 = wsh[(jj + 2) * 64 + oc];
            float w3 = wsh[(jj + 3) * 64 + oc];
            float4 x0 = *(const float4*)(xb + j);
            float4 x1 = *(const float4*)(xb + 384 + j);
            float4 x2 = *(const float4*)(xb + 768 + j);
            float4 x3 = *(const float4*)(xb + 1152 + j);
            acc0 += w0 * x0.x + w1 * x0.y + w2 * x0.z + w3 * x0.w;
            acc1 += w0 * x1.x + w1 * x1.y + w2 * x1.z + w3 * x1.w;
            acc2 += w0 * x2.x + w1 * x2.y + w2 * x2.z + w3 * x2.w;
            acc3 += w0 * x3.x + w1 * x3.y + w2 * x3.z + w3 * x3.w;
        }
    }
    float bb = cb[oc];
    int tp0 = tile * 16 + tq * 4;
    size_t o = ((size_t)b * TP + tp0) * COUT + oc;
    X[o]       = fmaxf(acc0 + bb, 0.f);
    X[o + 64]  = fmaxf(acc1 + bb, 0.f);
    X[o + 128] = fmaxf(acc2 + bb, 0.f);
    X[o + 192] = fmaxf(acc3 + bb, 0.f);
}

// ---------------------------------------------------------------------------
// Persistent LSTM: 64 blocks (one batch each) x 512 threads, one block/CU.
// Thread j owns gate cols j (i or f) and j+512 (g or o).
// ALL weights register-resident: 128+32 f16x2 dwords per col x 2 cols = 320
// VGPRs. __launch_bounds__(512, 2): min 2 waves/EU -> VGPR cap 512 (R2's
// implicit cap of 128 caused spill-reload stalls, VALUBusy 12%).
// h broadcast via LDS f16; c and gate accumulation fp32.
// ---------------------------------------------------------------------------
__device__ __forceinline__ float fsig(float x) {
    return 1.f / (1.f + __expf(-x));
}
__device__ __forceinline__ float ftanh(float x) {
    float xc = fminf(fmaxf(x, -15.f), 15.f);
    float e = __expf(2.f * xc);
    return (e - 1.f) / (e + 1.f);
}

#define DOTP(wa, wb, hw) do { a0 = fdot2((wa), (hw), a0); a1 = fdot2((wb), (hw), a1); } while (0)

__global__ __launch_bounds__(512, 2) void lstm_kernel(
        const float* __restrict__ X,
        const unsigned* __restrict__ whhR, const unsigned* __restrict__ wihR,
        const float* __restrict__ b_ih, const float* __restrict__ b_hh,
        const float* __restrict__ hx0, const float* __restrict__ cx0,
        const float* __restrict__ lin_w, const float* __restrict__ lin_b,
        float* __restrict__ out) {
    __shared__ __align__(16) _Float16 h_s[HID];
    __shared__ __align__(16) _Float16 x_s[COUT];
    __shared__ float2 fo_s[HID];     // pre-sigmoided f, o
    __shared__ float h32_s[HID];

    const int b = blockIdx.x, j = threadIdx.x;
    const int jb = j + 512;

    // ---- register-resident weights (coalesced loads) ----
    unsigned wA[128], wB[128], iA[32], iB[32];
#pragma unroll
    for (int d = 0; d < 128; d++) { wA[d] = whhR[d * 1024 + j]; wB[d] = whhR[d * 1024 + jb]; }
#pragma unroll
    for (int d = 0; d < 32; d++) { iA[d] = wihR[d * 1024 + j]; iB[d] = wihR[d * 1024 + jb]; }
    const float bias0 = b_ih[j] + b_hh[j];
    const float bias1 = b_ih[jb] + b_hh[jb];

    float c_reg = 0.f;
    if (j < HID) {
        c_reg = cx0[b * HID + j];
        h_s[j] = (_Float16)hx0[b * HID + j];
    }
    const float* Xb = X + (size_t)b * (TP * COUT);
    if (j < COUT) x_s[j] = (_Float16)Xb[j];
    __syncthreads();

    const uint4* hs4 = (const uint4*)h_s;   // 32 chunks of 8 h-values
    const uint4* xs4 = (const uint4*)x_s;   // 8 chunks

    for (int t = 0; t < TP; t++) {
        float xn = 0.f;
        if (j < COUT && t != TP - 1) xn = Xb[(t + 1) * COUT + j];

        float a0 = bias0, a1 = bias1;
#pragma unroll
        for (int d4 = 0; d4 < 32; d4++) {
            uint4 H = hs4[d4];
            DOTP(wA[4 * d4 + 0], wB[4 * d4 + 0], H.x);
            DOTP(wA[4 * d4 + 1], wB[4 * d4 + 1], H.y);
            DOTP(wA[4 * d4 + 2], wB[4 * d4 + 2], H.z);
            DOTP(wA[4 * d4 + 3], wB[4 * d4 + 3], H.w);
        }
#pragma unroll
        for (int d4 = 0; d4 < 8; d4++) {
            uint4 H = xs4[d4];
            DOTP(iA[4 * d4 + 0], iB[4 * d4 + 0], H.x);
            DOTP(iA[4 * d4 + 1], iB[4 * d4 + 1], H.y);
            DOTP(iA[4 * d4 + 2], iB[4 * d4 + 2], H.z);
            DOTP(iA[4 * d4 + 3], iB[4 * d4 + 3], H.w);
        }

        // upper waves (f,o owners) apply their sigmoids off the critical path
        if (j >= HID) fo_s[j - HID] = make_float2(fsig(a0), fsig(a1));
        __syncthreads();
        if (j < HID) {
            float2 fo = fo_s[j];               // sig(f), sig(o)
            c_reg = fo.x * c_reg + fsig(a0) * ftanh(a1);   // a0=i, a1=g
            float hh = fo.y * ftanh(c_reg);
            h_s[j] = (_Float16)hh;
            if (t == TP - 1) h32_s[j] = hh;
        }
        if (j < COUT) x_s[j] = (_Float16)xn;
        __syncthreads();
    }

    // epilogue: out[b] = h @ lin_w.T + lin_b  (fp32 h)
    if (j < OUT_N) {
        float s = lin_b[j];
        const float* lw = lin_w + j * HID;
#pragma unroll 4
        for (int k = 0; k < HID; k++) s += h32_s[k] * lw[k];
        out[b * OUT_N + j] = s;
    }
}

// ---------------------------------------------------------------------------
extern "C" void kernel_launch(void* const* d_in, const int* in_sizes, int n_in,
                              void* d_out, int out_size, void* d_ws, size_t ws_size,
                              hipStream_t stream) {
    const float* input  = (const float*)d_in[0];
    // d_in[1] = r (unused)
    const float* hx0    = (const float*)d_in[2];
    const float* cx0    = (const float*)d_in[3];
    const float* conv_w = (const float*)d_in[4];
    const float* conv_b = (const float*)d_in[5];
    const float* w_ih   = (const float*)d_in[6];
    const float* b_ih   = (const float*)d_in[7];
    const float* w_hh   = (const float*)d_in[8];
    const float* b_hh   = (const float*)d_in[9];
    const float* lin_w  = (const float*)d_in[10];
    const float* lin_b  = (const float*)d_in[11];

    float* ws = (float*)d_ws;
    float*    part  = ws;                          // 196608 floats
    float*    X     = ws + 196608;                 // 4194304 floats
    float*    wc2   = ws + 196608 + 4194304;       // 24576
    unsigned* whhR  = (unsigned*)(wc2 + 24576);    // 128*1024 dwords
    unsigned* wihR  = whhR + 128 * 1024;           // 32*1024 dwords

    pack_weights<<<1024, 128, 0, stream>>>(w_ih, w_hh, whhR, wihR);
    prep_conv_w<<<96, 256, 0, stream>>>(conv_w, wc2);
    norm_partial<<<dim3(B_N, NCHUNK), FIN, 0, stream>>>(input, part);
    conv_relu<<<dim3(B_N, 64), 256, 0, stream>>>(input, part, wc2, conv_b, X);
    lstm_kernel<<<B_N, 512, 0, stream>>>(
        X, whhR, wihR, b_ih, b_hh, hx0, cx0, lin_w, lin_b, (float*)d_out);
}

// Round 4
// 2527.434 us; speedup vs baseline: 3.6942x; 3.6942x over previous
//
#include <hip/hip_runtime.h>
#include <math.h>

#define B_N 64
#define T_N 3072
#define FIN 128
#define TP 1024      // conv output length
#define COUT 64
#define HID 256
#define G4 1024      // 4*HID
#define OUT_N 10
#define NCHUNK 24
#define CHUNK_T (T_N / NCHUNK)   // 128

// w_hh per gate-column: 128 f16x2 dwords = 32 uint4 chunks.
// 24 chunks in registers (48 named vec4 SSA values for 2 cols = 192 VGPRs),
// 8 chunks in LDS (8*1024*16 B = 128 KB).
#define WREG 24
#define WLDS 8

typedef _Float16 h2_t __attribute__((ext_vector_type(2)));
typedef unsigned u32x4 __attribute__((ext_vector_type(4)));

#if defined(__has_builtin)
#if __has_builtin(__builtin_amdgcn_fdot2)
#define HAVE_FDOT2 1
#endif
#endif

__device__ __forceinline__ float fdot2(unsigned w, unsigned h, float acc) {
#ifdef HAVE_FDOT2
    return __builtin_amdgcn_fdot2(__builtin_bit_cast(h2_t, w),
                                  __builtin_bit_cast(h2_t, h), acc, false);
#else
    h2_t wv = __builtin_bit_cast(h2_t, w), hv = __builtin_bit_cast(h2_t, h);
    return acc + (float)wv.x * (float)hv.x + (float)wv.y * (float)hv.y;
#endif
}

__device__ __forceinline__ unsigned pack2(float a, float b) {
    unsigned la = (unsigned)__builtin_bit_cast(unsigned short, (_Float16)a);
    unsigned lb = (unsigned)__builtin_bit_cast(unsigned short, (_Float16)b);
    return la | (lb << 16);
}

// ---------------------------------------------------------------------------
// Pack w_hh to f16x2 chunk layout [chunk c][col] (uint4 granules) and build
// wihT[k][1024] fp32 for the x-projection GEMM. grid 1024 (col), 128 thr (d).
// ---------------------------------------------------------------------------
__global__ void pack_weights(const float* __restrict__ w_ih,
                             const float* __restrict__ w_hh,
                             unsigned* __restrict__ whhR,   // [24][1024] uint4, flat dwords
                             unsigned* __restrict__ whhL,   // [8][1024] uint4, flat dwords
                             float* __restrict__ wihT) {    // [64][1024]
    int col = blockIdx.x, d = threadIdx.x;   // d = packed dword 0..127
    const float* wr = w_hh + col * HID;
    unsigned p = pack2(wr[2 * d], wr[2 * d + 1]);
    int c = d >> 2, r = d & 3;
    if (c < WREG) whhR[(c * 1024 + col) * 4 + r] = p;
    else          whhL[((c - WREG) * 1024 + col) * 4 + r] = p;
    if (d < COUT) wihT[d * 1024 + col] = w_ih[col * COUT + d];
}

// conv weight permute: wc2[j][oc], j = kk*128+ic
__global__ void prep_conv_w(const float* __restrict__ conv_w, float* __restrict__ wc2) {
    int i = blockIdx.x * 256 + threadIdx.x;
    if (i < 24576) {
        int j = i >> 6, oc = i & 63;
        int kk = j >> 7, ic = j & 127;
        wc2[i] = conv_w[(oc * 128 + ic) * 3 + kk];
    }
}

// ---------------------------------------------------------------------------
// partial sum-of-squares over time (F.normalize along dim=1)
// ---------------------------------------------------------------------------
__global__ void norm_partial(const float* __restrict__ in, float* __restrict__ part) {
    int b = blockIdx.x, ch = blockIdx.y, f = threadIdx.x;
    const float* p = in + ((size_t)b * T_N + (size_t)ch * CHUNK_T) * FIN + f;
    float s0 = 0.f, s1 = 0.f, s2 = 0.f, s3 = 0.f;
#pragma unroll
    for (int r = 0; r < CHUNK_T; r += 4) {
        float v0 = p[(r + 0) * FIN];
        float v1 = p[(r + 1) * FIN];
        float v2 = p[(r + 2) * FIN];
        float v3 = p[(r + 3) * FIN];
        s0 += v0 * v0; s1 += v1 * v1; s2 += v2 * v2; s3 += v3 * v3;
    }
    part[(b * NCHUNK + ch) * FIN + f] = (s0 + s1) + (s2 + s3);
}

// ---------------------------------------------------------------------------
// normalize + conv1d(k=3,stride=3) + bias + relu  (stride==K -> GEMM)
// ---------------------------------------------------------------------------
__global__ __launch_bounds__(256) void conv_relu(
        const float* __restrict__ in, const float* __restrict__ part,
        const float* __restrict__ wc2, const float* __restrict__ cb,
        float* __restrict__ X) {
    __shared__ __align__(16) float xs[16 * 384];
    __shared__ __align__(16) float wsh[96 * 64];
    __shared__ float invn[FIN];

    int b = blockIdx.x, tile = blockIdx.y;
    int tid = threadIdx.x;

    if (tid < FIN) {
        float s = 0.f;
#pragma unroll
        for (int c = 0; c < NCHUNK; c++) s += part[(b * NCHUNK + c) * FIN + tid];
        invn[tid] = rsqrtf(fmaxf(s, 1e-24f));
    }
    __syncthreads();

    const float* ip = in + ((size_t)b * T_N + (size_t)tile * 48) * FIN;
    for (int i = tid; i < 6144; i += 256) xs[i] = ip[i] * invn[i & 127];

    int oc = tid & 63, tq = tid >> 6;
    float acc0 = 0.f, acc1 = 0.f, acc2 = 0.f, acc3 = 0.f;
    const float* xb = xs + tq * 4 * 384;

    for (int c = 0; c < 4; c++) {
        __syncthreads();
        for (int i = tid; i < 6144; i += 256) wsh[i] = wc2[c * 6144 + i];
        __syncthreads();
#pragma unroll 8
        for (int jj = 0; jj < 96; jj += 4) {
            int j = c * 96 + jj;
            float w0 = wsh[(jj + 0) * 64 + oc];
            float w1 = wsh[(jj + 1) * 64 + oc];
            float w2 = wsh[(jj + 2) * 64 + oc];
            float w3 = wsh[(jj + 3) * 64 + oc];
            float4 x0 = *(const float4*)(xb + j);
            float4 x1 = *(const float4*)(xb + 384 + j);
            float4 x2 = *(const float4*)(xb + 768 + j);
            float4 x3 = *(const float4*)(xb + 1152 + j);
            acc0 += w0 * x0.x + w1 * x0.y + w2 * x0.z + w3 * x0.w;
            acc1 += w0 * x1.x + w1 * x1.y + w2 * x1.z + w3 * x1.w;
            acc2 += w0 * x2.x + w1 * x2.y + w2 * x2.z + w3 * x2.w;
            acc3 += w0 * x3.x + w1 * x3.y + w2 * x3.z + w3 * x3.w;
        }
    }
    float bb = cb[oc];
    int tp0 = tile * 16 + tq * 4;
    size_t o = ((size_t)b * TP + tp0) * COUT + oc;
    X[o]       = fmaxf(acc0 + bb, 0.f);
    X[o + 64]  = fmaxf(acc1 + bb, 0.f);
    X[o + 128] = fmaxf(acc2 + bb, 0.f);
    X[o + 192] = fmaxf(acc3 + bb, 0.f);
}

// ---------------------------------------------------------------------------
// x-projection GEMM: xg[b,t,j] = X[b,t,:] @ w_ih[j,:] + b_ih[j] + b_hh[j],
// stored f16 (xg magnitudes ~5e-3, f16 error negligible). Runs on all CUs.
// grid (64 b, 64 t-tiles of 16), 256 threads.
// ---------------------------------------------------------------------------
__global__ __launch_bounds__(256) void x_gemm(
        const float* __restrict__ X, const float* __restrict__ wihT,
        const float* __restrict__ b_ih, const float* __restrict__ b_hh,
        _Float16* __restrict__ xg) {
    __shared__ float xs[64 * 17];   // [k][r], padded
    int b = blockIdx.x, t0 = blockIdx.y * 16, tid = threadIdx.x;

    const float* Xp = X + ((size_t)b * TP + t0) * COUT;
    for (int i = tid; i < 1024; i += 256) {
        int r = i >> 6, k = i & 63;
        xs[k * 17 + r] = Xp[i];
    }
    __syncthreads();

#pragma unroll
    for (int jt = 0; jt < 4; jt++) {
        int jj = jt * 256 + tid;
        float bias = b_ih[jj] + b_hh[jj];
        float acc[16];
#pragma unroll
        for (int r = 0; r < 16; r++) acc[r] = bias;
        for (int k = 0; k < 64; k++) {
            float w = wihT[k * 1024 + jj];
#pragma unroll
            for (int r = 0; r < 16; r++) acc[r] += w * xs[k * 17 + r];
        }
#pragma unroll
        for (int r = 0; r < 16; r++)
            xg[((size_t)b * TP + t0 + r) * 1024 + jj] = (_Float16)acc[r];
    }
}

// ---------------------------------------------------------------------------
// Persistent LSTM: 64 blocks x 512 threads, one block/CU, 2 waves/EU pinned.
// Thread j owns gate cols j (i|f) and j+512 (g|o). w_hh f16x2:
//   chunks 0..23  -> 48 NAMED ext_vector SSA values (no alloca -> no scratch)
//   chunks 24..31 -> LDS (128 KB)
// x-projection precomputed (x_gemm) -> 2 f16 loads/thread/step.
// ---------------------------------------------------------------------------
__device__ __forceinline__ float fsig(float x) {
    return 1.f / (1.f + __expf(-x));
}
__device__ __forceinline__ float ftanh(float x) {
    float xc = fminf(fmaxf(x, -15.f), 15.f);
    float e = __expf(2.f * xc);
    return (e - 1.f) / (e + 1.f);
}

#define SM_WL   0
#define SM_H    131072
#define SM_FO   131584
#define SM_H32  133632
#define SM_SIZE 134656

#define REP24(M) M(0) M(1) M(2) M(3) M(4) M(5) M(6) M(7) M(8) M(9) M(10) M(11) \
                 M(12) M(13) M(14) M(15) M(16) M(17) M(18) M(19) M(20) M(21) M(22) M(23)
#define REP8(M)  M(0) M(1) M(2) M(3) M(4) M(5) M(6) M(7)

#define DECLW(n)  u32x4 wa##n, wb##n;
#define LOADW(n)  wa##n = whhR4[(n) * 1024 + j]; wb##n = whhR4[(n) * 1024 + j + 512];
#define DOTCH(n)  { u32x4 H = hs4[n]; \
    a0 = fdot2(wa##n[0], H[0], a0); a1 = fdot2(wb##n[0], H[0], a1); \
    a0 = fdot2(wa##n[1], H[1], a0); a1 = fdot2(wb##n[1], H[1], a1); \
    a0 = fdot2(wa##n[2], H[2], a0); a1 = fdot2(wb##n[2], H[2], a1); \
    a0 = fdot2(wa##n[3], H[3], a0); a1 = fdot2(wb##n[3], H[3], a1); }
#define DOTLDS(m) { u32x4 WA = wL[(m) * 1024 + j]; u32x4 WB = wL[(m) * 1024 + j + 512]; \
    u32x4 H = hs4[WREG + (m)]; \
    a0 = fdot2(WA[0], H[0], a0); a1 = fdot2(WB[0], H[0], a1); \
    a0 = fdot2(WA[1], H[1], a0); a1 = fdot2(WB[1], H[1], a1); \
    a0 = fdot2(WA[2], H[2], a0); a1 = fdot2(WB[2], H[2], a1); \
    a0 = fdot2(WA[3], H[3], a0); a1 = fdot2(WB[3], H[3], a1); }

__global__ __attribute__((amdgpu_flat_work_group_size(512, 512),
                          amdgpu_waves_per_eu(2, 2)))
void lstm_kernel(
        const u32x4* __restrict__ whhR4, const u32x4* __restrict__ whhL4,
        const _Float16* __restrict__ xg,
        const float* __restrict__ hx0, const float* __restrict__ cx0,
        const float* __restrict__ lin_w, const float* __restrict__ lin_b,
        float* __restrict__ out) {
    extern __shared__ char smem[];
    u32x4*    wL    = (u32x4*)(smem + SM_WL);       // [8][1024] uint4
    _Float16* h_s   = (_Float16*)(smem + SM_H);     // 256
    float2*   fo_s  = (float2*)(smem + SM_FO);      // 256
    float*    h32_s = (float*)(smem + SM_H32);      // 256

    const int b = blockIdx.x, j = threadIdx.x;

    // named-SSA register-resident w_hh chunks (192 VGPRs)
    REP24(DECLW)
    REP24(LOADW)

    // stage LDS-resident chunks
    for (int i = j; i < WLDS * 1024; i += 512) wL[i] = whhL4[i];

    float c_reg = 0.f;
    if (j < HID) {
        c_reg = cx0[b * HID + j];
        h_s[j] = (_Float16)hx0[b * HID + j];
    }
    const _Float16* Xg = xg + (size_t)b * TP * G4;
    _Float16 xa = Xg[j], xb = Xg[j + 512];
    __syncthreads();

    const u32x4* hs4 = (const u32x4*)h_s;   // 32 chunks of 8 h-values

    for (int t = 0; t < TP; t++) {
        _Float16 xan = (_Float16)0.f, xbn = (_Float16)0.f;
        if (t + 1 < TP) {
            xan = Xg[(t + 1) * G4 + j];
            xbn = Xg[(t + 1) * G4 + j + 512];
        }

        float a0 = (float)xa, a1 = (float)xb;   // bias folded into xg
        REP24(DOTCH)
        REP8(DOTLDS)

        float s0 = 0.f, s1 = 0.f;
        if (j >= HID) {
            fo_s[j - HID] = make_float2(fsig(a0), fsig(a1));   // sig(f), sig(o)
        } else {
            s0 = fsig(a0);    // sig(i)
            s1 = ftanh(a1);   // tanh(g)
        }
        __syncthreads();
        if (j < HID) {
            float2 fo = fo_s[j];
            c_reg = fo.x * c_reg + s0 * s1;
            float hh = fo.y * ftanh(c_reg);
            h_s[j] = (_Float16)hh;
            if (t == TP - 1) h32_s[j] = hh;
        }
        __syncthreads();
        xa = xan; xb = xbn;
    }

    // epilogue: out[b] = h @ lin_w.T + lin_b  (fp32 h)
    if (j < OUT_N) {
        float s = lin_b[j];
        const float* lw = lin_w + j * HID;
#pragma unroll 4
        for (int k = 0; k < HID; k++) s += h32_s[k] * lw[k];
        out[b * OUT_N + j] = s;
    }
}

// ---------------------------------------------------------------------------
extern "C" void kernel_launch(void* const* d_in, const int* in_sizes, int n_in,
                              void* d_out, int out_size, void* d_ws, size_t ws_size,
                              hipStream_t stream) {
    const float* input  = (const float*)d_in[0];
    // d_in[1] = r (unused)
    const float* hx0    = (const float*)d_in[2];
    const float* cx0    = (const float*)d_in[3];
    const float* conv_w = (const float*)d_in[4];
    const float* conv_b = (const float*)d_in[5];
    const float* w_ih   = (const float*)d_in[6];
    const float* b_ih   = (const float*)d_in[7];
    const float* w_hh   = (const float*)d_in[8];
    const float* b_hh   = (const float*)d_in[9];
    const float* lin_w  = (const float*)d_in[10];
    const float* lin_b  = (const float*)d_in[11];

    float* ws = (float*)d_ws;
    float*     part = ws;                      // 196608 floats
    float*     X    = part + 196608;           // 4194304 floats
    float*     wc2  = X + 4194304;             // 24576 floats
    float*     wihT = wc2 + 24576;             // 65536 floats
    unsigned*  whhR = (unsigned*)(wihT + 65536);  // 24*1024*4 dwords
    unsigned*  whhL = whhR + WREG * 1024 * 4;     // 8*1024*4 dwords
    _Float16*  xg   = (_Float16*)(whhL + WLDS * 1024 * 4);  // 64*1024*1024 halves

    (void)hipFuncSetAttribute((const void*)lstm_kernel,
                              hipFuncAttributeMaxDynamicSharedMemorySize, SM_SIZE);

    pack_weights<<<1024, 128, 0, stream>>>(w_ih, w_hh, whhR, whhL, wihT);
    prep_conv_w<<<96, 256, 0, stream>>>(conv_w, wc2);
    norm_partial<<<dim3(B_N, NCHUNK), FIN, 0, stream>>>(input, part);
    conv_relu<<<dim3(B_N, 64), 256, 0, stream>>>(input, part, wc2, conv_b, X);
    x_gemm<<<dim3(B_N, 64), 256, 0, stream>>>(X, wihT, b_ih, b_hh, xg);
    lstm_kernel<<<B_N, 512, SM_SIZE, stream>>>(
        (const u32x4*)whhR, (const u32x4*)whhL, xg,
        hx0, cx0, lin_w, lin_b, (float*)d_out);
}